// Round 8
// baseline (1777.455 us; speedup 1.0000x reference)
//
#include <hip/hip_runtime.h>
#include <hip/hip_bf16.h>

#define HIDDEN 256
#define BATCH  64
#define SEQ    2048

typedef float v2f __attribute__((ext_vector_type(2)));

__device__ __forceinline__ float tanh_fast(float x) {
    float e = __expf(2.0f * x);
    return 1.0f - 2.0f / (e + 1.0f);
}

// DPP cross-lane adds on the VALU pipe (keeps the CU-shared LDS pipe free)
#define DPP_ADD(v, CTRL)                                                        \
    (v + __int_as_float(__builtin_amdgcn_update_dpp(                            \
            0, __float_as_int(v), (CTRL), 0xF, 0xF, true)))
#define CTRL_XOR1 0xB1   // quad_perm [1,0,3,2]            = xor1
#define CTRL_XOR2 0x4E   // quad_perm [2,3,0,1]            = xor2
#define CTRL_HMIR 0x141  // row_half_mirror (l^7) == xor4 after quads uniform
#define CTRL_MIR  0x140  // row_mirror      (l^15) == xor8 after 8-uniform

// Opaque-def: forbids rematerialization of the weight loads.
#define KEEP(v) asm volatile("" : "+v"(v))

// LDS-only barrier: sync LDS handoff WITHOUT draining vmcnt.
#define BAR_LDS() do {                                                          \
    asm volatile("s_waitcnt lgkmcnt(0)\n\ts_barrier" ::: "memory");             \
    __builtin_amdgcn_sched_barrier(0);                                          \
} while (0)

// ---------------------------------------------------------------------------
// Phase 1: x_pre[row,h] = bias[h] + sum_d embed[x[row],d] * Wx[h,d]
// (32 rows/block, 256 thr, 16 rows x 2 cols per thread)
// ---------------------------------------------------------------------------
__global__ __launch_bounds__(256, 4)
void xpre_kernel(const int* __restrict__ x,
                 const float* __restrict__ embed,
                 const float* __restrict__ Wx,
                 const float* __restrict__ bias,
                 float* __restrict__ out) {
    const int tid = threadIdx.x;
    const int hh  = tid >> 7;        // row half: rows [16hh, 16hh+16)
    const int j2  = tid & 127;       // col pair {j2, j2+128}
    const long row0 = (long)blockIdx.x * 32;

    __shared__ int toks[32];
    __shared__ __align__(16) float e[32][HIDDEN];

    if (tid < 32) toks[tid] = x[row0 + tid];
    __syncthreads();

    #pragma unroll
    for (int r = 0; r < 32; ++r) {
        e[r][tid] = embed[(long)toks[r] * HIDDEN + tid];   // coalesced 1KB/row
    }
    __syncthreads();

    float acc0[16], acc1[16];
    const float b0 = bias[j2];
    const float b1 = bias[j2 + 128];
    #pragma unroll
    for (int r = 0; r < 16; ++r) { acc0[r] = b0; acc1[r] = b1; }

    const float* wrow0 = Wx + (size_t)j2 * HIDDEN;
    const float* wrow1 = Wx + (size_t)(j2 + 128) * HIDDEN;

    #pragma unroll 2
    for (int d0 = 0; d0 < HIDDEN; d0 += 4) {
        const float4 w0 = *(const float4*)(wrow0 + d0);
        const float4 w1 = *(const float4*)(wrow1 + d0);
        #pragma unroll
        for (int r = 0; r < 16; ++r) {
            const float4 ev = *(const float4*)&e[(hh << 4) + r][d0];  // broadcast
            float a = acc0[r];
            a = fmaf(w0.x, ev.x, a); a = fmaf(w0.y, ev.y, a);
            a = fmaf(w0.z, ev.z, a); a = fmaf(w0.w, ev.w, a);
            acc0[r] = a;
            float c = acc1[r];
            c = fmaf(w1.x, ev.x, c); c = fmaf(w1.y, ev.y, c);
            c = fmaf(w1.z, ev.z, c); c = fmaf(w1.w, ev.w, c);
            acc1[r] = c;
        }
    }

    #pragma unroll
    for (int r = 0; r < 16; ++r) {
        const long orow = (row0 + (hh << 4) + r) * HIDDEN;
        out[orow + j2]       = acc0[r];
        out[orow + j2 + 128] = acc1[r];
    }
}

// ---------------------------------------------------------------------------
// Phase 2: sequential scan. 1 block (1024 thr, 16 waves) per batch element.
// Thread (o = tid&15, pc = tid>>4): 4 columns {pc+64k}, h-slice h[16o..16o+15].
// Weights: 32 v2f = 64 VGPR. amdgpu_waves_per_eu(4,4) pins the allocator's
// occupancy target to the block's actual residency (16 waves/CU = 4/EU, cap
// 128 VGPR) so it has NO incentive to rematerialize/spill the weights --
// the L2 weight re-streaming was the 1.5 ms wall of rounds 2-7.
// Per step: 4 ds_read_b128 (4x broadcast), 32 pk_fma, 4 sums x 4-stage DPP
// butterfly, writer lanes o<4 do select + tanh + store. BAR_LDS per step.
// ---------------------------------------------------------------------------
__global__ __launch_bounds__(1024)
__attribute__((amdgpu_waves_per_eu(4, 4)))
void rnn_scan_kernel(const float* __restrict__ Wh,
                     float* __restrict__ out) {
    const int b   = blockIdx.x;
    const int tid = threadIdx.x;
    const int o   = tid & 15;    // h-slice index
    const int pc  = tid >> 4;    // column group [0,64)

    // 4 columns x 16 weights = 16 float4 -> 32 named v2f (64 VGPR)
#define LDWCOL(K)                                                               \
    const float* wp##K = Wh + (size_t)(pc + 64*(K)) * HIDDEN + (o << 4);        \
    const float4 f##K##a = *(const float4*)(wp##K);                             \
    const float4 f##K##b = *(const float4*)(wp##K + 4);                         \
    const float4 f##K##c = *(const float4*)(wp##K + 8);                         \
    const float4 f##K##d = *(const float4*)(wp##K + 12);                        \
    v2f w##K##0 = {f##K##a.x, f##K##a.y}; v2f w##K##1 = {f##K##a.z, f##K##a.w}; \
    v2f w##K##2 = {f##K##b.x, f##K##b.y}; v2f w##K##3 = {f##K##b.z, f##K##b.w}; \
    v2f w##K##4 = {f##K##c.x, f##K##c.y}; v2f w##K##5 = {f##K##c.z, f##K##c.w}; \
    v2f w##K##6 = {f##K##d.x, f##K##d.y}; v2f w##K##7 = {f##K##d.z, f##K##d.w}; \
    KEEP(w##K##0); KEEP(w##K##1); KEEP(w##K##2); KEEP(w##K##3);                 \
    KEEP(w##K##4); KEEP(w##K##5); KEEP(w##K##6); KEEP(w##K##7);
    LDWCOL(0) LDWCOL(1) LDWCOL(2) LDWCOL(3)
#undef LDWCOL

    // h layout: float f stored at slot f + 4*(f>>4)  (4-float pad per 16)
    __shared__ __align__(16) float hbuf[2][320];
    if (tid < 320) { hbuf[0][tid] = 0.0f; hbuf[1][tid] = 0.0f; }

    float* row = out + (size_t)b * SEQ * HIDDEN;
    const int col   = pc + (o << 6);            // writer (o<4) column: pc+64*o
    const int wslot = col + 4 * (col >> 4);     // padded LDS slot
    float xp = (o < 4) ? row[col] : 0.0f;       // x_pre at t=0

    __syncthreads();

    float* hcur = hbuf[0];
    float* hnxt = hbuf[1];

    for (int t = 0; t < SEQ; ++t) {
        float xpn = 0.0f;
        if (o < 4 && t + 1 < SEQ) xpn = row[(size_t)(t + 1) * HIDDEN + col];

        // read my 16-float h slice (4 x b128; 16 distinct addrs/wave -> 4x
        // broadcast, <=2-way bank alias = free)
        const float* hb = hcur + 20 * o;
        const float4 hva = *(const float4*)(hb);
        const float4 hvb = *(const float4*)(hb + 4);
        const float4 hvc = *(const float4*)(hb + 8);
        const float4 hvd = *(const float4*)(hb + 12);
        const v2f h0 = {hva.x, hva.y}, h1 = {hva.z, hva.w};
        const v2f h2 = {hvb.x, hvb.y}, h3 = {hvb.z, hvb.w};
        const v2f h4 = {hvc.x, hvc.y}, h5 = {hvc.z, hvc.w};
        const v2f h6 = {hvd.x, hvd.y}, h7 = {hvd.z, hvd.w};

        // 4 columns x 8 pk_fma
#define MACCOL(K, S)                                                            \
        {   v2f a = {0.f, 0.f}, c = {0.f, 0.f};                                 \
            a = __builtin_elementwise_fma(w##K##0, h0, a);                      \
            c = __builtin_elementwise_fma(w##K##1, h1, c);                      \
            a = __builtin_elementwise_fma(w##K##2, h2, a);                      \
            c = __builtin_elementwise_fma(w##K##3, h3, c);                      \
            a = __builtin_elementwise_fma(w##K##4, h4, a);                      \
            c = __builtin_elementwise_fma(w##K##5, h5, c);                      \
            a = __builtin_elementwise_fma(w##K##6, h6, a);                      \
            c = __builtin_elementwise_fma(w##K##7, h7, c);                      \
            const v2f sv = a + c;                                               \
            S = sv.x + sv.y; }
        float s0, s1, s2, s3;
        MACCOL(0, s0) MACCOL(1, s1) MACCOL(2, s2) MACCOL(3, s3)
#undef MACCOL

        // 16-lane butterfly on the VALU pipe: xor1, xor2, ~xor4, ~xor8
#define RED4(S)                                                                 \
        S = DPP_ADD(S, CTRL_XOR1);                                              \
        S = DPP_ADD(S, CTRL_XOR2);                                              \
        S = DPP_ADD(S, CTRL_HMIR);                                              \
        S = DPP_ADD(S, CTRL_MIR);
        RED4(s0) RED4(s1) RED4(s2) RED4(s3)
#undef RED4

        // select sum (o&3) via cndmask tree; tanh on all lanes, writers store
        const int k = o & 3;
        const float t01 = (k & 1) ? s1 : s0;
        const float t23 = (k & 1) ? s3 : s2;
        const float s   = (k & 2) ? t23 : t01;

        const float h = tanh_fast(xp + s);

        if (o < 4) {
            row[(size_t)t * HIDDEN + col] = h;   // fire-and-forget store
            hnxt[wslot] = h;                     // padded LDS handoff
        }
        BAR_LDS();                               // lgkmcnt-only barrier
        float* tmp = hcur; hcur = hnxt; hnxt = tmp;
        xp = xpn;
    }
}

extern "C" void kernel_launch(void* const* d_in, const int* in_sizes, int n_in,
                              void* d_out, int out_size, void* d_ws, size_t ws_size,
                              hipStream_t stream) {
    const int*   x     = (const int*)d_in[0];
    const float* embed = (const float*)d_in[1];
    const float* Wx    = (const float*)d_in[2];
    const float* Wxb   = (const float*)d_in[3];
    const float* Wh    = (const float*)d_in[4];
    float* out = (float*)d_out;

    const int nrows = BATCH * SEQ;                  // 131072, 32 rows/block
    xpre_kernel<<<nrows / 32, 256, 0, stream>>>(x, embed, Wx, Wxb, out);

    rnn_scan_kernel<<<BATCH, 1024, 0, stream>>>(Wh, out);
}

// Round 10
// 1706.687 us; speedup vs baseline: 1.0415x; 1.0415x over previous
//
#include <hip/hip_runtime.h>
#include <hip/hip_bf16.h>

#define HIDDEN 256
#define BATCH  64
#define SEQ    2048

typedef float v2f __attribute__((ext_vector_type(2)));

__device__ __forceinline__ float tanh_fast(float x) {
    float e = __expf(2.0f * x);
    return 1.0f - 2.0f / (e + 1.0f);
}

// DPP cross-lane adds on the VALU pipe (keeps the CU-shared LDS pipe free)
#define DPP_ADD(v, CTRL)                                                        \
    (v + __int_as_float(__builtin_amdgcn_update_dpp(                            \
            0, __float_as_int(v), (CTRL), 0xF, 0xF, true)))
#define CTRL_XOR1 0xB1   // quad_perm [1,0,3,2]            = xor1
#define CTRL_XOR2 0x4E   // quad_perm [2,3,0,1]            = xor2
#define CTRL_HMIR 0x141  // row_half_mirror (l^7) == xor4 after quads uniform
#define CTRL_MIR  0x140  // row_mirror      (l^15) == xor8 after 8-uniform

// Opaque-def: forbids rematerialization of the weight loads.
#define KEEP(v) asm volatile("" : "+v"(v))

// LDS-only barrier: sync LDS handoff WITHOUT draining vmcnt.
#define BAR_LDS() do {                                                          \
    asm volatile("s_waitcnt lgkmcnt(0)\n\ts_barrier" ::: "memory");             \
    __builtin_amdgcn_sched_barrier(0);                                          \
} while (0)

// ---------------------------------------------------------------------------
// Phase 1: x_pre[row,h] = bias[h] + sum_d embed[x[row],d] * Wx[h,d]
// (32 rows/block, 256 thr, 16 rows x 2 cols per thread) — unchanged.
// ---------------------------------------------------------------------------
__global__ __launch_bounds__(256, 4)
void xpre_kernel(const int* __restrict__ x,
                 const float* __restrict__ embed,
                 const float* __restrict__ Wx,
                 const float* __restrict__ bias,
                 float* __restrict__ out) {
    const int tid = threadIdx.x;
    const int hh  = tid >> 7;        // row half: rows [16hh, 16hh+16)
    const int j2  = tid & 127;       // col pair {j2, j2+128}
    const long row0 = (long)blockIdx.x * 32;

    __shared__ int toks[32];
    __shared__ __align__(16) float e[32][HIDDEN];

    if (tid < 32) toks[tid] = x[row0 + tid];
    __syncthreads();

    #pragma unroll
    for (int r = 0; r < 32; ++r) {
        e[r][tid] = embed[(long)toks[r] * HIDDEN + tid];   // coalesced 1KB/row
    }
    __syncthreads();

    float acc0[16], acc1[16];
    const float b0 = bias[j2];
    const float b1 = bias[j2 + 128];
    #pragma unroll
    for (int r = 0; r < 16; ++r) { acc0[r] = b0; acc1[r] = b1; }

    const float* wrow0 = Wx + (size_t)j2 * HIDDEN;
    const float* wrow1 = Wx + (size_t)(j2 + 128) * HIDDEN;

    #pragma unroll 2
    for (int d0 = 0; d0 < HIDDEN; d0 += 4) {
        const float4 w0 = *(const float4*)(wrow0 + d0);
        const float4 w1 = *(const float4*)(wrow1 + d0);
        #pragma unroll
        for (int r = 0; r < 16; ++r) {
            const float4 ev = *(const float4*)&e[(hh << 4) + r][d0];  // broadcast
            float a = acc0[r];
            a = fmaf(w0.x, ev.x, a); a = fmaf(w0.y, ev.y, a);
            a = fmaf(w0.z, ev.z, a); a = fmaf(w0.w, ev.w, a);
            acc0[r] = a;
            float c = acc1[r];
            c = fmaf(w1.x, ev.x, c); c = fmaf(w1.y, ev.y, c);
            c = fmaf(w1.z, ev.z, c); c = fmaf(w1.w, ev.w, c);
            acc1[r] = c;
        }
    }

    #pragma unroll
    for (int r = 0; r < 16; ++r) {
        const long orow = (row0 + (hh << 4) + r) * HIDDEN;
        out[orow + j2]       = acc0[r];
        out[orow + j2 + 128] = acc1[r];
    }
}

// ---------------------------------------------------------------------------
// Phase 2: sequential scan. 1 block (512 thr, 8 waves) per batch element.
// Thread (o = tid&15, pc = tid>>4): 8 columns {pc+32k}, h-slice h[16o..16o+15].
// Weights: 64 v2f = 128 VGPR. Occupancy attributes pin the allocator:
// flat_work_group_size(512,512) + waves_per_eu(2,2) -> exactly 2 waves/EU,
// VGPR cap 256 >= demand ~176, and NO incentive to spill for occupancy.
// (Rounds 1-8 post-mortem: min-style launch_bounds/waves_per_eu only set a
// floor; the allocator chased max occupancy and spilled/remat'ed the weights
// every step -> the ~1.5 ms L2-streaming wall. VGPR_Count >= 160 = success.)
// Per step: 4 ds_read_b128, 64 pk_fma, 16-lane DPP butterfly, writers (o<8)
// select + tanh + store. BAR_LDS (lgkmcnt-only) per step.
// ---------------------------------------------------------------------------
__global__ __attribute__((amdgpu_flat_work_group_size(512, 512),
                          amdgpu_waves_per_eu(2, 2)))
void rnn_scan_kernel(const float* __restrict__ Wh,
                     float* __restrict__ out) {
    const int b   = blockIdx.x;
    const int tid = threadIdx.x;
    const int o   = tid & 15;    // h-slice index
    const int pc  = tid >> 4;    // column base [0,32)

    // 8 columns x 16 weights = 32 float4 -> 64 named v2f (128 VGPR)
#define LDWCOL(K)                                                               \
    const float* wp##K = Wh + (size_t)(pc + 32*(K)) * HIDDEN + (o << 4);        \
    const float4 f##K##a = *(const float4*)(wp##K);                             \
    const float4 f##K##b = *(const float4*)(wp##K + 4);                         \
    const float4 f##K##c = *(const float4*)(wp##K + 8);                         \
    const float4 f##K##d = *(const float4*)(wp##K + 12);                        \
    v2f w##K##0 = {f##K##a.x, f##K##a.y}; v2f w##K##1 = {f##K##a.z, f##K##a.w}; \
    v2f w##K##2 = {f##K##b.x, f##K##b.y}; v2f w##K##3 = {f##K##b.z, f##K##b.w}; \
    v2f w##K##4 = {f##K##c.x, f##K##c.y}; v2f w##K##5 = {f##K##c.z, f##K##c.w}; \
    v2f w##K##6 = {f##K##d.x, f##K##d.y}; v2f w##K##7 = {f##K##d.z, f##K##d.w}; \
    KEEP(w##K##0); KEEP(w##K##1); KEEP(w##K##2); KEEP(w##K##3);                 \
    KEEP(w##K##4); KEEP(w##K##5); KEEP(w##K##6); KEEP(w##K##7);
    LDWCOL(0) LDWCOL(1) LDWCOL(2) LDWCOL(3)
    LDWCOL(4) LDWCOL(5) LDWCOL(6) LDWCOL(7)
#undef LDWCOL

    // h layout: float f stored at slot f + 4*(f>>4)  (4-float pad per 16)
    __shared__ __align__(16) float hbuf[2][320];
    if (tid < 320) { hbuf[0][tid] = 0.0f; hbuf[1][tid] = 0.0f; }

    float* row = out + (size_t)b * SEQ * HIDDEN;
    const int col   = pc + (o << 5);            // writer (o<8) column
    const int wslot = col + 4 * (col >> 4);     // padded LDS slot
    float xp = (o < 8) ? row[col] : 0.0f;       // x_pre at t=0

    __syncthreads();

    float* hcur = hbuf[0];
    float* hnxt = hbuf[1];

    for (int t = 0; t < SEQ; ++t) {
        float xpn = 0.0f;
        if (o < 8 && t + 1 < SEQ) xpn = row[(size_t)(t + 1) * HIDDEN + col];

        // read my 16-float h slice (4 x b128, 2-way bank alias = free)
        const float* hb = hcur + 20 * o;
        const float4 hva = *(const float4*)(hb);
        const float4 hvb = *(const float4*)(hb + 4);
        const float4 hvc = *(const float4*)(hb + 8);
        const float4 hvd = *(const float4*)(hb + 12);
        const v2f h0 = {hva.x, hva.y}, h1 = {hva.z, hva.w};
        const v2f h2 = {hvb.x, hvb.y}, h3 = {hvb.z, hvb.w};
        const v2f h4 = {hvc.x, hvc.y}, h5 = {hvc.z, hvc.w};
        const v2f h6 = {hvd.x, hvd.y}, h7 = {hvd.z, hvd.w};

        // 8 columns x 8 pk_fma
#define MACCOL(K, S)                                                            \
        {   v2f a = {0.f, 0.f}, c = {0.f, 0.f};                                 \
            a = __builtin_elementwise_fma(w##K##0, h0, a);                      \
            c = __builtin_elementwise_fma(w##K##1, h1, c);                      \
            a = __builtin_elementwise_fma(w##K##2, h2, a);                      \
            c = __builtin_elementwise_fma(w##K##3, h3, c);                      \
            a = __builtin_elementwise_fma(w##K##4, h4, a);                      \
            c = __builtin_elementwise_fma(w##K##5, h5, c);                      \
            a = __builtin_elementwise_fma(w##K##6, h6, a);                      \
            c = __builtin_elementwise_fma(w##K##7, h7, c);                      \
            const v2f sv = a + c;                                               \
            S = sv.x + sv.y; }
        float s0, s1, s2, s3, s4, s5, s6, s7;
        MACCOL(0, s0) MACCOL(1, s1) MACCOL(2, s2) MACCOL(3, s3)
        MACCOL(4, s4) MACCOL(5, s5) MACCOL(6, s6) MACCOL(7, s7)
#undef MACCOL

        // 16-lane butterfly on the VALU pipe: xor1, xor2, ~xor4, ~xor8
#define RED4(S)                                                                 \
        S = DPP_ADD(S, CTRL_XOR1);                                              \
        S = DPP_ADD(S, CTRL_XOR2);                                              \
        S = DPP_ADD(S, CTRL_HMIR);                                              \
        S = DPP_ADD(S, CTRL_MIR);
        RED4(s0) RED4(s1) RED4(s2) RED4(s3)
        RED4(s4) RED4(s5) RED4(s6) RED4(s7)
#undef RED4

        // select sum (o&7) via cndmask tree; tanh on all lanes, writers store
        const int k = o & 7;
        const float t01 = (k & 1) ? s1 : s0;
        const float t23 = (k & 1) ? s3 : s2;
        const float t45 = (k & 1) ? s5 : s4;
        const float t67 = (k & 1) ? s7 : s6;
        const float u0  = (k & 2) ? t23 : t01;
        const float u1  = (k & 2) ? t67 : t45;
        const float s   = (k & 4) ? u1 : u0;

        const float h = tanh_fast(xp + s);

        if (o < 8) {
            row[(size_t)t * HIDDEN + col] = h;   // fire-and-forget store
            hnxt[wslot] = h;                     // padded LDS handoff
        }
        BAR_LDS();                               // lgkmcnt-only barrier
        float* tmp = hcur; hcur = hnxt; hnxt = tmp;
        xp = xpn;
    }
}

extern "C" void kernel_launch(void* const* d_in, const int* in_sizes, int n_in,
                              void* d_out, int out_size, void* d_ws, size_t ws_size,
                              hipStream_t stream) {
    const int*   x     = (const int*)d_in[0];
    const float* embed = (const float*)d_in[1];
    const float* Wx    = (const float*)d_in[2];
    const float* Wxb   = (const float*)d_in[3];
    const float* Wh    = (const float*)d_in[4];
    float* out = (float*)d_out;

    const int nrows = BATCH * SEQ;                  // 131072, 32 rows/block
    xpre_kernel<<<nrows / 32, 256, 0, stream>>>(x, embed, Wx, Wxb, out);

    rnn_scan_kernel<<<BATCH, 512, 0, stream>>>(Wh, out);
}

// Round 13
// 1396.157 us; speedup vs baseline: 1.2731x; 1.2224x over previous
//
#include <hip/hip_runtime.h>
#include <hip/hip_bf16.h>

#define HIDDEN 256
#define BATCH  64
#define SEQ    2048

// ---------------------------------------------------------------------------
// Phase 1: x_pre[row,h] = bias[h] + sum_d embed[x[row],d] * Wx[h,d]
// (32 rows/block, 256 thr, 16 rows x 2 cols per thread) — proven, unchanged.
// ---------------------------------------------------------------------------
__global__ __launch_bounds__(256, 4)
void xpre_kernel(const int* __restrict__ x,
                 const float* __restrict__ embed,
                 const float* __restrict__ Wx,
                 const float* __restrict__ bias,
                 float* __restrict__ out) {
    const int tid = threadIdx.x;
    const int hh  = tid >> 7;
    const int j2  = tid & 127;
    const long row0 = (long)blockIdx.x * 32;

    __shared__ int toks[32];
    __shared__ __align__(16) float e[32][HIDDEN];

    if (tid < 32) toks[tid] = x[row0 + tid];
    __syncthreads();

    #pragma unroll
    for (int r = 0; r < 32; ++r) {
        e[r][tid] = embed[(long)toks[r] * HIDDEN + tid];
    }
    __syncthreads();

    float acc0[16], acc1[16];
    const float b0 = bias[j2];
    const float b1 = bias[j2 + 128];
    #pragma unroll
    for (int r = 0; r < 16; ++r) { acc0[r] = b0; acc1[r] = b1; }

    const float* wrow0 = Wx + (size_t)j2 * HIDDEN;
    const float* wrow1 = Wx + (size_t)(j2 + 128) * HIDDEN;

    #pragma unroll 2
    for (int d0 = 0; d0 < HIDDEN; d0 += 4) {
        const float4 w0 = *(const float4*)(wrow0 + d0);
        const float4 w1 = *(const float4*)(wrow1 + d0);
        #pragma unroll
        for (int r = 0; r < 16; ++r) {
            const float4 ev = *(const float4*)&e[(hh << 4) + r][d0];
            float a = acc0[r];
            a = fmaf(w0.x, ev.x, a); a = fmaf(w0.y, ev.y, a);
            a = fmaf(w0.z, ev.z, a); a = fmaf(w0.w, ev.w, a);
            acc0[r] = a;
            float c = acc1[r];
            c = fmaf(w1.x, ev.x, c); c = fmaf(w1.y, ev.y, c);
            c = fmaf(w1.z, ev.z, c); c = fmaf(w1.w, ev.w, c);
            acc1[r] = c;
        }
    }

    #pragma unroll
    for (int r = 0; r < 16; ++r) {
        const long orow = (row0 + (hh << 4) + r) * HIDDEN;
        out[orow + j2]       = acc0[r];
        out[orow + j2 + 128] = acc1[r];
    }
}

// ---------------------------------------------------------------------------
// Phase 2: whole-loop-in-asm scan. 64 blocks x 512 thr (8 waves, 2/EU).
// Thread (o=tid&15, pc=tid>>4): 8 cols {pc+32k}, h-slice h[16o..16o+15].
// Weights hand-pinned at v[128:255]. FIXES vs R12: (1) weight dwordx4 loads
// at byte offsets 0/16/32/48 (16 CONSECUTIVE floats; 64/128/192 loaded the
// wrong columns -> absmax 1.31); (2) s_nop 1 before xor2-stage DPP (2-wait
// hazard); (3) 2-deep x_pre prefetch with counted s_waitcnt vmcnt(2) --
// every FIN waits exactly to the row loaded 2 halves (~900cy) earlier, the
// newest {load,store} stay in flight across the lgkmcnt-only barrier.
// ---------------------------------------------------------------------------

#define MAC_ASM(RD) \
  "ds_read_b128 v[48:51], " RD "\n\t" \
  "ds_read_b128 v[52:55], " RD " offset:16\n\t" \
  "ds_read_b128 v[56:59], " RD " offset:32\n\t" \
  "ds_read_b128 v[60:63], " RD " offset:48\n\t" \
  "s_waitcnt lgkmcnt(0)\n\t" \
  "v_pk_mul_f32 v[64:65], v[128:129], v[48:49]\n\t" \
  "v_pk_mul_f32 v[66:67], v[144:145], v[48:49]\n\t" \
  "v_pk_mul_f32 v[68:69], v[160:161], v[48:49]\n\t" \
  "v_pk_mul_f32 v[70:71], v[176:177], v[48:49]\n\t" \
  "v_pk_mul_f32 v[72:73], v[192:193], v[48:49]\n\t" \
  "v_pk_mul_f32 v[74:75], v[208:209], v[48:49]\n\t" \
  "v_pk_mul_f32 v[76:77], v[224:225], v[48:49]\n\t" \
  "v_pk_mul_f32 v[78:79], v[240:241], v[48:49]\n\t" \
  "v_pk_fma_f32 v[64:65], v[130:131], v[50:51], v[64:65]\n\t" \
  "v_pk_fma_f32 v[66:67], v[146:147], v[50:51], v[66:67]\n\t" \
  "v_pk_fma_f32 v[68:69], v[162:163], v[50:51], v[68:69]\n\t" \
  "v_pk_fma_f32 v[70:71], v[178:179], v[50:51], v[70:71]\n\t" \
  "v_pk_fma_f32 v[72:73], v[194:195], v[50:51], v[72:73]\n\t" \
  "v_pk_fma_f32 v[74:75], v[210:211], v[50:51], v[74:75]\n\t" \
  "v_pk_fma_f32 v[76:77], v[226:227], v[50:51], v[76:77]\n\t" \
  "v_pk_fma_f32 v[78:79], v[242:243], v[50:51], v[78:79]\n\t" \
  "v_pk_fma_f32 v[64:65], v[132:133], v[52:53], v[64:65]\n\t" \
  "v_pk_fma_f32 v[66:67], v[148:149], v[52:53], v[66:67]\n\t" \
  "v_pk_fma_f32 v[68:69], v[164:165], v[52:53], v[68:69]\n\t" \
  "v_pk_fma_f32 v[70:71], v[180:181], v[52:53], v[70:71]\n\t" \
  "v_pk_fma_f32 v[72:73], v[196:197], v[52:53], v[72:73]\n\t" \
  "v_pk_fma_f32 v[74:75], v[212:213], v[52:53], v[74:75]\n\t" \
  "v_pk_fma_f32 v[76:77], v[228:229], v[52:53], v[76:77]\n\t" \
  "v_pk_fma_f32 v[78:79], v[244:245], v[52:53], v[78:79]\n\t" \
  "v_pk_fma_f32 v[64:65], v[134:135], v[54:55], v[64:65]\n\t" \
  "v_pk_fma_f32 v[66:67], v[150:151], v[54:55], v[66:67]\n\t" \
  "v_pk_fma_f32 v[68:69], v[166:167], v[54:55], v[68:69]\n\t" \
  "v_pk_fma_f32 v[70:71], v[182:183], v[54:55], v[70:71]\n\t" \
  "v_pk_fma_f32 v[72:73], v[198:199], v[54:55], v[72:73]\n\t" \
  "v_pk_fma_f32 v[74:75], v[214:215], v[54:55], v[74:75]\n\t" \
  "v_pk_fma_f32 v[76:77], v[230:231], v[54:55], v[76:77]\n\t" \
  "v_pk_fma_f32 v[78:79], v[246:247], v[54:55], v[78:79]\n\t" \
  "v_pk_fma_f32 v[64:65], v[136:137], v[56:57], v[64:65]\n\t" \
  "v_pk_fma_f32 v[66:67], v[152:153], v[56:57], v[66:67]\n\t" \
  "v_pk_fma_f32 v[68:69], v[168:169], v[56:57], v[68:69]\n\t" \
  "v_pk_fma_f32 v[70:71], v[184:185], v[56:57], v[70:71]\n\t" \
  "v_pk_fma_f32 v[72:73], v[200:201], v[56:57], v[72:73]\n\t" \
  "v_pk_fma_f32 v[74:75], v[216:217], v[56:57], v[74:75]\n\t" \
  "v_pk_fma_f32 v[76:77], v[232:233], v[56:57], v[76:77]\n\t" \
  "v_pk_fma_f32 v[78:79], v[248:249], v[56:57], v[78:79]\n\t" \
  "v_pk_fma_f32 v[64:65], v[138:139], v[58:59], v[64:65]\n\t" \
  "v_pk_fma_f32 v[66:67], v[154:155], v[58:59], v[66:67]\n\t" \
  "v_pk_fma_f32 v[68:69], v[170:171], v[58:59], v[68:69]\n\t" \
  "v_pk_fma_f32 v[70:71], v[186:187], v[58:59], v[70:71]\n\t" \
  "v_pk_fma_f32 v[72:73], v[202:203], v[58:59], v[72:73]\n\t" \
  "v_pk_fma_f32 v[74:75], v[218:219], v[58:59], v[74:75]\n\t" \
  "v_pk_fma_f32 v[76:77], v[234:235], v[58:59], v[76:77]\n\t" \
  "v_pk_fma_f32 v[78:79], v[250:251], v[58:59], v[78:79]\n\t" \
  "v_pk_fma_f32 v[64:65], v[140:141], v[60:61], v[64:65]\n\t" \
  "v_pk_fma_f32 v[66:67], v[156:157], v[60:61], v[66:67]\n\t" \
  "v_pk_fma_f32 v[68:69], v[172:173], v[60:61], v[68:69]\n\t" \
  "v_pk_fma_f32 v[70:71], v[188:189], v[60:61], v[70:71]\n\t" \
  "v_pk_fma_f32 v[72:73], v[204:205], v[60:61], v[72:73]\n\t" \
  "v_pk_fma_f32 v[74:75], v[220:221], v[60:61], v[74:75]\n\t" \
  "v_pk_fma_f32 v[76:77], v[236:237], v[60:61], v[76:77]\n\t" \
  "v_pk_fma_f32 v[78:79], v[252:253], v[60:61], v[78:79]\n\t" \
  "v_pk_fma_f32 v[64:65], v[142:143], v[62:63], v[64:65]\n\t" \
  "v_pk_fma_f32 v[66:67], v[158:159], v[62:63], v[66:67]\n\t" \
  "v_pk_fma_f32 v[68:69], v[174:175], v[62:63], v[68:69]\n\t" \
  "v_pk_fma_f32 v[70:71], v[190:191], v[62:63], v[70:71]\n\t" \
  "v_pk_fma_f32 v[72:73], v[206:207], v[62:63], v[72:73]\n\t" \
  "v_pk_fma_f32 v[74:75], v[222:223], v[62:63], v[74:75]\n\t" \
  "v_pk_fma_f32 v[76:77], v[238:239], v[62:63], v[76:77]\n\t" \
  "v_pk_fma_f32 v[78:79], v[254:255], v[62:63], v[78:79]\n\t" \
  "v_add_f32 v80, v64, v65\n\t" \
  "v_add_f32 v81, v66, v67\n\t" \
  "v_add_f32 v82, v68, v69\n\t" \
  "v_add_f32 v83, v70, v71\n\t" \
  "v_add_f32 v84, v72, v73\n\t" \
  "v_add_f32 v85, v74, v75\n\t" \
  "v_add_f32 v86, v76, v77\n\t" \
  "v_add_f32 v87, v78, v79\n\t"

// merge-reduce over the 16 o-lanes; lane o ends with total for col pc+32*(o&7)
#define RED_ASM \
  "v_add_f32_dpp v80, v80, v80 row_ror:8 row_mask:0xf bank_mask:0xf\n\t" \
  "v_add_f32_dpp v81, v81, v81 row_ror:8 row_mask:0xf bank_mask:0xf\n\t" \
  "v_add_f32_dpp v82, v82, v82 row_ror:8 row_mask:0xf bank_mask:0xf\n\t" \
  "v_add_f32_dpp v83, v83, v83 row_ror:8 row_mask:0xf bank_mask:0xf\n\t" \
  "v_add_f32_dpp v84, v84, v84 row_ror:8 row_mask:0xf bank_mask:0xf\n\t" \
  "v_add_f32_dpp v85, v85, v85 row_ror:8 row_mask:0xf bank_mask:0xf\n\t" \
  "v_add_f32_dpp v86, v86, v86 row_ror:8 row_mask:0xf bank_mask:0xf\n\t" \
  "v_add_f32_dpp v87, v87, v87 row_ror:8 row_mask:0xf bank_mask:0xf\n\t" \
  "v_cndmask_b32 v88, v81, v80, s[24:25]\n\t" \
  "v_cndmask_b32 v89, v83, v82, s[24:25]\n\t" \
  "v_cndmask_b32 v90, v85, v84, s[24:25]\n\t" \
  "v_cndmask_b32 v91, v87, v86, s[24:25]\n\t" \
  "v_cndmask_b32 v80, v80, v81, s[24:25]\n\t" \
  "v_cndmask_b32 v82, v82, v83, s[24:25]\n\t" \
  "v_cndmask_b32 v84, v84, v85, s[24:25]\n\t" \
  "v_cndmask_b32 v86, v86, v87, s[24:25]\n\t" \
  "v_add_f32_dpp v80, v88, v80 quad_perm:[1,0,3,2] row_mask:0xf bank_mask:0xf\n\t" \
  "v_add_f32_dpp v82, v89, v82 quad_perm:[1,0,3,2] row_mask:0xf bank_mask:0xf\n\t" \
  "v_add_f32_dpp v84, v90, v84 quad_perm:[1,0,3,2] row_mask:0xf bank_mask:0xf\n\t" \
  "v_add_f32_dpp v86, v91, v86 quad_perm:[1,0,3,2] row_mask:0xf bank_mask:0xf\n\t" \
  "v_cndmask_b32 v88, v82, v80, s[26:27]\n\t" \
  "v_cndmask_b32 v89, v86, v84, s[26:27]\n\t" \
  "v_cndmask_b32 v80, v80, v82, s[26:27]\n\t" \
  "v_cndmask_b32 v84, v84, v86, s[26:27]\n\t" \
  "s_nop 1\n\t" \
  "v_add_f32_dpp v80, v88, v80 quad_perm:[2,3,0,1] row_mask:0xf bank_mask:0xf\n\t" \
  "v_add_f32_dpp v84, v89, v84 quad_perm:[2,3,0,1] row_mask:0xf bank_mask:0xf\n\t" \
  "v_cndmask_b32 v88, v84, v80, s[28:29]\n\t" \
  "v_cndmask_b32 v80, v80, v84, s[28:29]\n\t" \
  "s_nop 1\n\t" \
  "v_add_f32_dpp v80, v88, v80 row_ror:4 row_mask:0xf bank_mask:0xf\n\t"

// finish: counted wait, xp add, tanh, masked stores, prefetch-reg rotate,
// pointer advance, lgkmcnt-only barrier. Store offset: ptr is 2 rows ahead.
#define FIN_ASM(WR, XP, MD, MS) \
  "s_waitcnt vmcnt(2)\n\t" \
  "v_add_f32 v99, v80, " XP "\n\t" \
  "v_mul_f32 v93, 0x4038AA3B, v99\n\t" \
  "v_exp_f32 v94, v93\n\t" \
  "s_nop 0\n\t" \
  "v_add_f32 v94, 1.0, v94\n\t" \
  "v_rcp_f32 v95, v94\n\t" \
  "s_nop 0\n\t" \
  "v_fma_f32 v99, -2.0, v95, v96\n\t" \
  "s_and_saveexec_b64 s[20:21], s[22:23]\n\t" \
  "global_store_dword v[100:101], v99, off offset:-2048\n\t" \
  "ds_write_b32 " WR ", v99\n\t" \
  "s_mov_b64 exec, s[20:21]\n\t" \
  "v_mov_b32 " MD ", " MS "\n\t" \
  "v_add_co_u32 v100, vcc, 0x400, v100\n\t" \
  "v_addc_co_u32 v101, vcc, v101, 0, vcc\n\t" \
  "s_waitcnt lgkmcnt(0)\n\t" \
  "s_barrier\n\t"

__global__ __attribute__((amdgpu_flat_work_group_size(512, 512)))
void rnn_scan_kernel(const float* __restrict__ Wh,
                     float* __restrict__ out) {
    const int tid = threadIdx.x;
    const int o   = tid & 15;
    const int pc  = tid >> 4;
    const int b   = blockIdx.x;

    // buf0 @ base+0, buf1 @ base+2048; padded slot(f)=f+4*(f>>4)
    __shared__ __align__(16) float hraw[1024];
    hraw[tid] = 0.0f; hraw[tid + 512] = 0.0f;
    __syncthreads();

    unsigned lbase = (unsigned)(unsigned long long)
                     (__attribute__((address_space(3))) char*)hraw;
    const int col  = pc + 32 * (o & 7);
    const int slot = col + 4 * (col >> 4);
    const unsigned rda = lbase + 80u * (unsigned)o;           // read buf0
    const unsigned rdb = rda + 2048u;                         // read buf1
    const unsigned wra = lbase + 2048u + 4u * (unsigned)slot; // write buf1
    const unsigned wrb = wra - 2048u;                         // write buf0

    const float* xa = out + ((size_t)b * SEQ + 2) * HIDDEN + col; // ptr@row2
    const unsigned xlo = (unsigned)(size_t)xa;
    const unsigned xhi = (unsigned)((size_t)xa >> 32);

    const float* wp0 = Wh + (size_t)(pc +   0) * HIDDEN + 16 * o;
    const float* wp1 = Wh + (size_t)(pc +  32) * HIDDEN + 16 * o;
    const float* wp2 = Wh + (size_t)(pc +  64) * HIDDEN + 16 * o;
    const float* wp3 = Wh + (size_t)(pc +  96) * HIDDEN + 16 * o;
    const float* wp4 = Wh + (size_t)(pc + 128) * HIDDEN + 16 * o;
    const float* wp5 = Wh + (size_t)(pc + 160) * HIDDEN + 16 * o;
    const float* wp6 = Wh + (size_t)(pc + 192) * HIDDEN + 16 * o;
    const float* wp7 = Wh + (size_t)(pc + 224) * HIDDEN + 16 * o;

    asm volatile(
        // ---- prologue: weights -> v[128:255] (16 CONSECUTIVE floats each:
        // byte offsets 0/16/32/48), xp regs, lane masks ----
        "v_mov_b32 v100, %[xlo]\n\t"
        "v_mov_b32 v101, %[xhi]\n\t"
        "v_mov_b32 v96, 1.0\n\t"
        "global_load_dwordx4 v[128:131], %[wp0], off\n\t"
        "global_load_dwordx4 v[132:135], %[wp0], off offset:16\n\t"
        "global_load_dwordx4 v[136:139], %[wp0], off offset:32\n\t"
        "global_load_dwordx4 v[140:143], %[wp0], off offset:48\n\t"
        "global_load_dwordx4 v[144:147], %[wp1], off\n\t"
        "global_load_dwordx4 v[148:151], %[wp1], off offset:16\n\t"
        "global_load_dwordx4 v[152:155], %[wp1], off offset:32\n\t"
        "global_load_dwordx4 v[156:159], %[wp1], off offset:48\n\t"
        "global_load_dwordx4 v[160:163], %[wp2], off\n\t"
        "global_load_dwordx4 v[164:167], %[wp2], off offset:16\n\t"
        "global_load_dwordx4 v[168:171], %[wp2], off offset:32\n\t"
        "global_load_dwordx4 v[172:175], %[wp2], off offset:48\n\t"
        "global_load_dwordx4 v[176:179], %[wp3], off\n\t"
        "global_load_dwordx4 v[180:183], %[wp3], off offset:16\n\t"
        "global_load_dwordx4 v[184:187], %[wp3], off offset:32\n\t"
        "global_load_dwordx4 v[188:191], %[wp3], off offset:48\n\t"
        "global_load_dwordx4 v[192:195], %[wp4], off\n\t"
        "global_load_dwordx4 v[196:199], %[wp4], off offset:16\n\t"
        "global_load_dwordx4 v[200:203], %[wp4], off offset:32\n\t"
        "global_load_dwordx4 v[204:207], %[wp4], off offset:48\n\t"
        "global_load_dwordx4 v[208:211], %[wp5], off\n\t"
        "global_load_dwordx4 v[212:215], %[wp5], off offset:16\n\t"
        "global_load_dwordx4 v[216:219], %[wp5], off offset:32\n\t"
        "global_load_dwordx4 v[220:223], %[wp5], off offset:48\n\t"
        "global_load_dwordx4 v[224:227], %[wp6], off\n\t"
        "global_load_dwordx4 v[228:231], %[wp6], off offset:16\n\t"
        "global_load_dwordx4 v[232:235], %[wp6], off offset:32\n\t"
        "global_load_dwordx4 v[236:239], %[wp6], off offset:48\n\t"
        "global_load_dwordx4 v[240:243], %[wp7], off\n\t"
        "global_load_dwordx4 v[244:247], %[wp7], off offset:16\n\t"
        "global_load_dwordx4 v[248:251], %[wp7], off offset:32\n\t"
        "global_load_dwordx4 v[252:255], %[wp7], off offset:48\n\t"
        "global_load_dword v97,  v[100:101], off offset:-2048\n\t"  // row 0
        "global_load_dword v103, v[100:101], off offset:-1024\n\t"  // row 1
        "v_and_b32 v88, 1, %[vo]\n\t"
        "v_cmp_eq_u32 s[24:25], 1, v88\n\t"
        "v_and_b32 v88, 2, %[vo]\n\t"
        "v_cmp_eq_u32 s[26:27], 2, v88\n\t"
        "v_and_b32 v88, 4, %[vo]\n\t"
        "v_cmp_eq_u32 s[28:29], 4, v88\n\t"
        "v_cmp_gt_u32 s[22:23], 8, %[vo]\n\t"
        "s_movk_i32 s30, 0x400\n\t"
        "s_waitcnt vmcnt(0)\n\t"
        // ---- main loop: 1024 iterations x 2 steps; ptr = row t+2 at half A
        "RNN%=:\n\t"
        // half A top: prefetch row t+2 -> v102 (last iter: dummy row 2047)
        "s_cmp_eq_u32 s30, 1\n\t"
        "s_cbranch_scc1 LDA%=\n\t"
        "global_load_dword v102, v[100:101], off\n\t"
        "s_branch LCA%=\n\t"
        "LDA%=:\n\t"
        "global_load_dword v102, v[100:101], off offset:-1024\n\t"
        "LCA%=:\n\t"
        MAC_ASM("%[rda]")
        RED_ASM
        FIN_ASM("%[wra]", "v97", "v98", "v103")
        // half B top: prefetch row t+3 -> v103 (last iter: dummy row 2047)
        "s_cmp_eq_u32 s30, 1\n\t"
        "s_cbranch_scc1 LDB%=\n\t"
        "global_load_dword v103, v[100:101], off\n\t"
        "s_branch LCB%=\n\t"
        "LDB%=:\n\t"
        "global_load_dword v103, v[100:101], off offset:-2048\n\t"
        "LCB%=:\n\t"
        MAC_ASM("%[rdb]")
        RED_ASM
        FIN_ASM("%[wrb]", "v98", "v97", "v102")
        "s_sub_u32 s30, s30, 1\n\t"
        "s_cmp_lg_u32 s30, 0\n\t"
        "s_cbranch_scc1 RNN%=\n\t"
        "s_waitcnt vmcnt(0) lgkmcnt(0)\n\t"
        :
        : [wp0] "v"(wp0), [wp1] "v"(wp1), [wp2] "v"(wp2), [wp3] "v"(wp3),
          [wp4] "v"(wp4), [wp5] "v"(wp5), [wp6] "v"(wp6), [wp7] "v"(wp7),
          [xlo] "v"(xlo), [xhi] "v"(xhi),
          [rda] "v"(rda), [rdb] "v"(rdb), [wra] "v"(wra), [wrb] "v"(wrb),
          [vo]  "v"(o)
        : "memory", "vcc", "scc",
          "s20","s21","s22","s23","s24","s25","s26","s27","s28","s29","s30",
          "v48","v49","v50","v51","v52","v53","v54","v55",
          "v56","v57","v58","v59","v60","v61","v62","v63",
          "v64","v65","v66","v67","v68","v69","v70","v71",
          "v72","v73","v74","v75","v76","v77","v78","v79",
          "v80","v81","v82","v83","v84","v85","v86","v87",
          "v88","v89","v90","v91","v92","v93","v94","v95",
          "v96","v97","v98","v99","v100","v101","v102","v103",
          "v104","v105","v106","v107","v108","v109","v110","v111",
          "v112","v113","v114","v115","v116","v117","v118","v119",
          "v120","v121","v122","v123","v124","v125","v126","v127",
          "v128","v129","v130","v131","v132","v133","v134","v135",
          "v136","v137","v138","v139","v140","v141","v142","v143",
          "v144","v145","v146","v147","v148","v149","v150","v151",
          "v152","v153","v154","v155","v156","v157","v158","v159",
          "v160","v161","v162","v163","v164","v165","v166","v167",
          "v168","v169","v170","v171","v172","v173","v174","v175",
          "v176","v177","v178","v179","v180","v181","v182","v183",
          "v184","v185","v186","v187","v188","v189","v190","v191",
          "v192","v193","v194","v195","v196","v197","v198","v199",
          "v200","v201","v202","v203","v204","v205","v206","v207",
          "v208","v209","v210","v211","v212","v213","v214","v215",
          "v216","v217","v218","v219","v220","v221","v222","v223",
          "v224","v225","v226","v227","v228","v229","v230","v231",
          "v232","v233","v234","v235","v236","v237","v238","v239",
          "v240","v241","v242","v243","v244","v245","v246","v247",
          "v248","v249","v250","v251","v252","v253","v254","v255");
}

extern "C" void kernel_launch(void* const* d_in, const int* in_sizes, int n_in,
                              void* d_out, int out_size, void* d_ws, size_t ws_size,
                              hipStream_t stream) {
    const int*   x     = (const int*)d_in[0];
    const float* embed = (const float*)d_in[1];
    const float* Wx    = (const float*)d_in[2];
    const float* Wxb   = (const float*)d_in[3];
    const float* Wh    = (const float*)d_in[4];
    float* out = (float*)d_out;

    const int nrows = BATCH * SEQ;                  // 131072, 32 rows/block
    xpre_kernel<<<nrows / 32, 256, 0, stream>>>(x, embed, Wx, Wxb, out);

    rnn_scan_kernel<<<BATCH, 512, 0, stream>>>(Wh, out);
}

// Round 14
// 1371.586 us; speedup vs baseline: 1.2959x; 1.0179x over previous
//
#include <hip/hip_runtime.h>
#include <hip/hip_bf16.h>

#define HIDDEN 256
#define BATCH  64
#define SEQ    2048

// ---------------------------------------------------------------------------
// Phase 1: x_pre[row,h] = bias[h] + sum_d embed[x[row],d] * Wx[h,d]
// (32 rows/block, 256 thr, 16 rows x 2 cols per thread) — proven, unchanged.
// ---------------------------------------------------------------------------
__global__ __launch_bounds__(256, 4)
void xpre_kernel(const int* __restrict__ x,
                 const float* __restrict__ embed,
                 const float* __restrict__ Wx,
                 const float* __restrict__ bias,
                 float* __restrict__ out) {
    const int tid = threadIdx.x;
    const int hh  = tid >> 7;
    const int j2  = tid & 127;
    const long row0 = (long)blockIdx.x * 32;

    __shared__ int toks[32];
    __shared__ __align__(16) float e[32][HIDDEN];

    if (tid < 32) toks[tid] = x[row0 + tid];
    __syncthreads();

    #pragma unroll
    for (int r = 0; r < 32; ++r) {
        e[r][tid] = embed[(long)toks[r] * HIDDEN + tid];
    }
    __syncthreads();

    float acc0[16], acc1[16];
    const float b0 = bias[j2];
    const float b1 = bias[j2 + 128];
    #pragma unroll
    for (int r = 0; r < 16; ++r) { acc0[r] = b0; acc1[r] = b1; }

    const float* wrow0 = Wx + (size_t)j2 * HIDDEN;
    const float* wrow1 = Wx + (size_t)(j2 + 128) * HIDDEN;

    #pragma unroll 2
    for (int d0 = 0; d0 < HIDDEN; d0 += 4) {
        const float4 w0 = *(const float4*)(wrow0 + d0);
        const float4 w1 = *(const float4*)(wrow1 + d0);
        #pragma unroll
        for (int r = 0; r < 16; ++r) {
            const float4 ev = *(const float4*)&e[(hh << 4) + r][d0];
            float a = acc0[r];
            a = fmaf(w0.x, ev.x, a); a = fmaf(w0.y, ev.y, a);
            a = fmaf(w0.z, ev.z, a); a = fmaf(w0.w, ev.w, a);
            acc0[r] = a;
            float c = acc1[r];
            c = fmaf(w1.x, ev.x, c); c = fmaf(w1.y, ev.y, c);
            c = fmaf(w1.z, ev.z, c); c = fmaf(w1.w, ev.w, c);
            acc1[r] = c;
        }
    }

    #pragma unroll
    for (int r = 0; r < 16; ++r) {
        const long orow = (row0 + (hh << 4) + r) * HIDDEN;
        out[orow + j2]       = acc0[r];
        out[orow + j2 + 128] = acc1[r];
    }
}

// ---------------------------------------------------------------------------
// Phase 2: whole-loop-in-asm scan (R13 base, PASSING at 1141us) + R14 change:
// counted lgkmcnt interleave — MAC split into 4 FMA groups gated by
// lgkmcnt(3)/(2)/(1)/(0) so the CU's 384-cyc LDS serve time overlaps the
// 488-cyc VALU issue instead of preceding it (DS queue completes in-order,
// so counted lgkm on a DS-only queue is exact). FIN: ds_write before
// global_store (earlier LDS retire -> shorter pre-barrier lgkm drain).
// ---------------------------------------------------------------------------

#define MAC_ASM(RD) \
  "ds_read_b128 v[48:51], " RD "\n\t" \
  "ds_read_b128 v[52:55], " RD " offset:16\n\t" \
  "ds_read_b128 v[56:59], " RD " offset:32\n\t" \
  "ds_read_b128 v[60:63], " RD " offset:48\n\t" \
  "s_waitcnt lgkmcnt(3)\n\t" \
  "v_pk_mul_f32 v[64:65], v[128:129], v[48:49]\n\t" \
  "v_pk_mul_f32 v[66:67], v[144:145], v[48:49]\n\t" \
  "v_pk_mul_f32 v[68:69], v[160:161], v[48:49]\n\t" \
  "v_pk_mul_f32 v[70:71], v[176:177], v[48:49]\n\t" \
  "v_pk_mul_f32 v[72:73], v[192:193], v[48:49]\n\t" \
  "v_pk_mul_f32 v[74:75], v[208:209], v[48:49]\n\t" \
  "v_pk_mul_f32 v[76:77], v[224:225], v[48:49]\n\t" \
  "v_pk_mul_f32 v[78:79], v[240:241], v[48:49]\n\t" \
  "v_pk_fma_f32 v[64:65], v[130:131], v[50:51], v[64:65]\n\t" \
  "v_pk_fma_f32 v[66:67], v[146:147], v[50:51], v[66:67]\n\t" \
  "v_pk_fma_f32 v[68:69], v[162:163], v[50:51], v[68:69]\n\t" \
  "v_pk_fma_f32 v[70:71], v[178:179], v[50:51], v[70:71]\n\t" \
  "v_pk_fma_f32 v[72:73], v[194:195], v[50:51], v[72:73]\n\t" \
  "v_pk_fma_f32 v[74:75], v[210:211], v[50:51], v[74:75]\n\t" \
  "v_pk_fma_f32 v[76:77], v[226:227], v[50:51], v[76:77]\n\t" \
  "v_pk_fma_f32 v[78:79], v[242:243], v[50:51], v[78:79]\n\t" \
  "s_waitcnt lgkmcnt(2)\n\t" \
  "v_pk_fma_f32 v[64:65], v[132:133], v[52:53], v[64:65]\n\t" \
  "v_pk_fma_f32 v[66:67], v[148:149], v[52:53], v[66:67]\n\t" \
  "v_pk_fma_f32 v[68:69], v[164:165], v[52:53], v[68:69]\n\t" \
  "v_pk_fma_f32 v[70:71], v[180:181], v[52:53], v[70:71]\n\t" \
  "v_pk_fma_f32 v[72:73], v[196:197], v[52:53], v[72:73]\n\t" \
  "v_pk_fma_f32 v[74:75], v[212:213], v[52:53], v[74:75]\n\t" \
  "v_pk_fma_f32 v[76:77], v[228:229], v[52:53], v[76:77]\n\t" \
  "v_pk_fma_f32 v[78:79], v[244:245], v[52:53], v[78:79]\n\t" \
  "v_pk_fma_f32 v[64:65], v[134:135], v[54:55], v[64:65]\n\t" \
  "v_pk_fma_f32 v[66:67], v[150:151], v[54:55], v[66:67]\n\t" \
  "v_pk_fma_f32 v[68:69], v[166:167], v[54:55], v[68:69]\n\t" \
  "v_pk_fma_f32 v[70:71], v[182:183], v[54:55], v[70:71]\n\t" \
  "v_pk_fma_f32 v[72:73], v[198:199], v[54:55], v[72:73]\n\t" \
  "v_pk_fma_f32 v[74:75], v[214:215], v[54:55], v[74:75]\n\t" \
  "v_pk_fma_f32 v[76:77], v[230:231], v[54:55], v[76:77]\n\t" \
  "v_pk_fma_f32 v[78:79], v[246:247], v[54:55], v[78:79]\n\t" \
  "s_waitcnt lgkmcnt(1)\n\t" \
  "v_pk_fma_f32 v[64:65], v[136:137], v[56:57], v[64:65]\n\t" \
  "v_pk_fma_f32 v[66:67], v[152:153], v[56:57], v[66:67]\n\t" \
  "v_pk_fma_f32 v[68:69], v[168:169], v[56:57], v[68:69]\n\t" \
  "v_pk_fma_f32 v[70:71], v[184:185], v[56:57], v[70:71]\n\t" \
  "v_pk_fma_f32 v[72:73], v[200:201], v[56:57], v[72:73]\n\t" \
  "v_pk_fma_f32 v[74:75], v[216:217], v[56:57], v[74:75]\n\t" \
  "v_pk_fma_f32 v[76:77], v[232:233], v[56:57], v[76:77]\n\t" \
  "v_pk_fma_f32 v[78:79], v[248:249], v[56:57], v[78:79]\n\t" \
  "v_pk_fma_f32 v[64:65], v[138:139], v[58:59], v[64:65]\n\t" \
  "v_pk_fma_f32 v[66:67], v[154:155], v[58:59], v[66:67]\n\t" \
  "v_pk_fma_f32 v[68:69], v[170:171], v[58:59], v[68:69]\n\t" \
  "v_pk_fma_f32 v[70:71], v[186:187], v[58:59], v[70:71]\n\t" \
  "v_pk_fma_f32 v[72:73], v[202:203], v[58:59], v[72:73]\n\t" \
  "v_pk_fma_f32 v[74:75], v[218:219], v[58:59], v[74:75]\n\t" \
  "v_pk_fma_f32 v[76:77], v[234:235], v[58:59], v[76:77]\n\t" \
  "v_pk_fma_f32 v[78:79], v[250:251], v[58:59], v[78:79]\n\t" \
  "s_waitcnt lgkmcnt(0)\n\t" \
  "v_pk_fma_f32 v[64:65], v[140:141], v[60:61], v[64:65]\n\t" \
  "v_pk_fma_f32 v[66:67], v[156:157], v[60:61], v[66:67]\n\t" \
  "v_pk_fma_f32 v[68:69], v[172:173], v[60:61], v[68:69]\n\t" \
  "v_pk_fma_f32 v[70:71], v[188:189], v[60:61], v[70:71]\n\t" \
  "v_pk_fma_f32 v[72:73], v[204:205], v[60:61], v[72:73]\n\t" \
  "v_pk_fma_f32 v[74:75], v[220:221], v[60:61], v[74:75]\n\t" \
  "v_pk_fma_f32 v[76:77], v[236:237], v[60:61], v[76:77]\n\t" \
  "v_pk_fma_f32 v[78:79], v[252:253], v[60:61], v[78:79]\n\t" \
  "v_pk_fma_f32 v[64:65], v[142:143], v[62:63], v[64:65]\n\t" \
  "v_pk_fma_f32 v[66:67], v[158:159], v[62:63], v[66:67]\n\t" \
  "v_pk_fma_f32 v[68:69], v[174:175], v[62:63], v[68:69]\n\t" \
  "v_pk_fma_f32 v[70:71], v[190:191], v[62:63], v[70:71]\n\t" \
  "v_pk_fma_f32 v[72:73], v[206:207], v[62:63], v[72:73]\n\t" \
  "v_pk_fma_f32 v[74:75], v[222:223], v[62:63], v[74:75]\n\t" \
  "v_pk_fma_f32 v[76:77], v[238:239], v[62:63], v[76:77]\n\t" \
  "v_pk_fma_f32 v[78:79], v[254:255], v[62:63], v[78:79]\n\t" \
  "v_add_f32 v80, v64, v65\n\t" \
  "v_add_f32 v81, v66, v67\n\t" \
  "v_add_f32 v82, v68, v69\n\t" \
  "v_add_f32 v83, v70, v71\n\t" \
  "v_add_f32 v84, v72, v73\n\t" \
  "v_add_f32 v85, v74, v75\n\t" \
  "v_add_f32 v86, v76, v77\n\t" \
  "v_add_f32 v87, v78, v79\n\t"

// merge-reduce over the 16 o-lanes; lane o ends with total for col pc+32*(o&7)
#define RED_ASM \
  "v_add_f32_dpp v80, v80, v80 row_ror:8 row_mask:0xf bank_mask:0xf\n\t" \
  "v_add_f32_dpp v81, v81, v81 row_ror:8 row_mask:0xf bank_mask:0xf\n\t" \
  "v_add_f32_dpp v82, v82, v82 row_ror:8 row_mask:0xf bank_mask:0xf\n\t" \
  "v_add_f32_dpp v83, v83, v83 row_ror:8 row_mask:0xf bank_mask:0xf\n\t" \
  "v_add_f32_dpp v84, v84, v84 row_ror:8 row_mask:0xf bank_mask:0xf\n\t" \
  "v_add_f32_dpp v85, v85, v85 row_ror:8 row_mask:0xf bank_mask:0xf\n\t" \
  "v_add_f32_dpp v86, v86, v86 row_ror:8 row_mask:0xf bank_mask:0xf\n\t" \
  "v_add_f32_dpp v87, v87, v87 row_ror:8 row_mask:0xf bank_mask:0xf\n\t" \
  "v_cndmask_b32 v88, v81, v80, s[24:25]\n\t" \
  "v_cndmask_b32 v89, v83, v82, s[24:25]\n\t" \
  "v_cndmask_b32 v90, v85, v84, s[24:25]\n\t" \
  "v_cndmask_b32 v91, v87, v86, s[24:25]\n\t" \
  "v_cndmask_b32 v80, v80, v81, s[24:25]\n\t" \
  "v_cndmask_b32 v82, v82, v83, s[24:25]\n\t" \
  "v_cndmask_b32 v84, v84, v85, s[24:25]\n\t" \
  "v_cndmask_b32 v86, v86, v87, s[24:25]\n\t" \
  "v_add_f32_dpp v80, v88, v80 quad_perm:[1,0,3,2] row_mask:0xf bank_mask:0xf\n\t" \
  "v_add_f32_dpp v82, v89, v82 quad_perm:[1,0,3,2] row_mask:0xf bank_mask:0xf\n\t" \
  "v_add_f32_dpp v84, v90, v84 quad_perm:[1,0,3,2] row_mask:0xf bank_mask:0xf\n\t" \
  "v_add_f32_dpp v86, v91, v86 quad_perm:[1,0,3,2] row_mask:0xf bank_mask:0xf\n\t" \
  "v_cndmask_b32 v88, v82, v80, s[26:27]\n\t" \
  "v_cndmask_b32 v89, v86, v84, s[26:27]\n\t" \
  "v_cndmask_b32 v80, v80, v82, s[26:27]\n\t" \
  "v_cndmask_b32 v84, v84, v86, s[26:27]\n\t" \
  "s_nop 1\n\t" \
  "v_add_f32_dpp v80, v88, v80 quad_perm:[2,3,0,1] row_mask:0xf bank_mask:0xf\n\t" \
  "v_add_f32_dpp v84, v89, v84 quad_perm:[2,3,0,1] row_mask:0xf bank_mask:0xf\n\t" \
  "v_cndmask_b32 v88, v84, v80, s[28:29]\n\t" \
  "v_cndmask_b32 v80, v80, v84, s[28:29]\n\t" \
  "s_nop 1\n\t" \
  "v_add_f32_dpp v80, v88, v80 row_ror:4 row_mask:0xf bank_mask:0xf\n\t"

// finish: counted vmcnt wait, xp add, tanh, ds_write FIRST then global store,
// prefetch-reg rotate, pointer advance, lgkmcnt-only barrier.
#define FIN_ASM(WR, XP, MD, MS) \
  "s_waitcnt vmcnt(2)\n\t" \
  "v_add_f32 v99, v80, " XP "\n\t" \
  "v_mul_f32 v93, 0x4038AA3B, v99\n\t" \
  "v_exp_f32 v94, v93\n\t" \
  "s_nop 0\n\t" \
  "v_add_f32 v94, 1.0, v94\n\t" \
  "v_rcp_f32 v95, v94\n\t" \
  "s_nop 0\n\t" \
  "v_fma_f32 v99, -2.0, v95, v96\n\t" \
  "s_and_saveexec_b64 s[20:21], s[22:23]\n\t" \
  "ds_write_b32 " WR ", v99\n\t" \
  "global_store_dword v[100:101], v99, off offset:-2048\n\t" \
  "s_mov_b64 exec, s[20:21]\n\t" \
  "v_mov_b32 " MD ", " MS "\n\t" \
  "v_add_co_u32 v100, vcc, 0x400, v100\n\t" \
  "v_addc_co_u32 v101, vcc, v101, 0, vcc\n\t" \
  "s_waitcnt lgkmcnt(0)\n\t" \
  "s_barrier\n\t"

__global__ __attribute__((amdgpu_flat_work_group_size(512, 512)))
void rnn_scan_kernel(const float* __restrict__ Wh,
                     float* __restrict__ out) {
    const int tid = threadIdx.x;
    const int o   = tid & 15;
    const int pc  = tid >> 4;
    const int b   = blockIdx.x;

    // buf0 @ base+0, buf1 @ base+2048; padded slot(f)=f+4*(f>>4)
    __shared__ __align__(16) float hraw[1024];
    hraw[tid] = 0.0f; hraw[tid + 512] = 0.0f;
    __syncthreads();

    unsigned lbase = (unsigned)(unsigned long long)
                     (__attribute__((address_space(3))) char*)hraw;
    const int col  = pc + 32 * (o & 7);
    const int slot = col + 4 * (col >> 4);
    const unsigned rda = lbase + 80u * (unsigned)o;           // read buf0
    const unsigned rdb = rda + 2048u;                         // read buf1
    const unsigned wra = lbase + 2048u + 4u * (unsigned)slot; // write buf1
    const unsigned wrb = wra - 2048u;                         // write buf0

    const float* xa = out + ((size_t)b * SEQ + 2) * HIDDEN + col; // ptr@row2
    const unsigned xlo = (unsigned)(size_t)xa;
    const unsigned xhi = (unsigned)((size_t)xa >> 32);

    const float* wp0 = Wh + (size_t)(pc +   0) * HIDDEN + 16 * o;
    const float* wp1 = Wh + (size_t)(pc +  32) * HIDDEN + 16 * o;
    const float* wp2 = Wh + (size_t)(pc +  64) * HIDDEN + 16 * o;
    const float* wp3 = Wh + (size_t)(pc +  96) * HIDDEN + 16 * o;
    const float* wp4 = Wh + (size_t)(pc + 128) * HIDDEN + 16 * o;
    const float* wp5 = Wh + (size_t)(pc + 160) * HIDDEN + 16 * o;
    const float* wp6 = Wh + (size_t)(pc + 192) * HIDDEN + 16 * o;
    const float* wp7 = Wh + (size_t)(pc + 224) * HIDDEN + 16 * o;

    asm volatile(
        // ---- prologue: weights -> v[128:255] (16 consecutive floats each),
        // xp regs, lane masks ----
        "v_mov_b32 v100, %[xlo]\n\t"
        "v_mov_b32 v101, %[xhi]\n\t"
        "v_mov_b32 v96, 1.0\n\t"
        "global_load_dwordx4 v[128:131], %[wp0], off\n\t"
        "global_load_dwordx4 v[132:135], %[wp0], off offset:16\n\t"
        "global_load_dwordx4 v[136:139], %[wp0], off offset:32\n\t"
        "global_load_dwordx4 v[140:143], %[wp0], off offset:48\n\t"
        "global_load_dwordx4 v[144:147], %[wp1], off\n\t"
        "global_load_dwordx4 v[148:151], %[wp1], off offset:16\n\t"
        "global_load_dwordx4 v[152:155], %[wp1], off offset:32\n\t"
        "global_load_dwordx4 v[156:159], %[wp1], off offset:48\n\t"
        "global_load_dwordx4 v[160:163], %[wp2], off\n\t"
        "global_load_dwordx4 v[164:167], %[wp2], off offset:16\n\t"
        "global_load_dwordx4 v[168:171], %[wp2], off offset:32\n\t"
        "global_load_dwordx4 v[172:175], %[wp2], off offset:48\n\t"
        "global_load_dwordx4 v[176:179], %[wp3], off\n\t"
        "global_load_dwordx4 v[180:183], %[wp3], off offset:16\n\t"
        "global_load_dwordx4 v[184:187], %[wp3], off offset:32\n\t"
        "global_load_dwordx4 v[188:191], %[wp3], off offset:48\n\t"
        "global_load_dwordx4 v[192:195], %[wp4], off\n\t"
        "global_load_dwordx4 v[196:199], %[wp4], off offset:16\n\t"
        "global_load_dwordx4 v[200:203], %[wp4], off offset:32\n\t"
        "global_load_dwordx4 v[204:207], %[wp4], off offset:48\n\t"
        "global_load_dwordx4 v[208:211], %[wp5], off\n\t"
        "global_load_dwordx4 v[212:215], %[wp5], off offset:16\n\t"
        "global_load_dwordx4 v[216:219], %[wp5], off offset:32\n\t"
        "global_load_dwordx4 v[220:223], %[wp5], off offset:48\n\t"
        "global_load_dwordx4 v[224:227], %[wp6], off\n\t"
        "global_load_dwordx4 v[228:231], %[wp6], off offset:16\n\t"
        "global_load_dwordx4 v[232:235], %[wp6], off offset:32\n\t"
        "global_load_dwordx4 v[236:239], %[wp6], off offset:48\n\t"
        "global_load_dwordx4 v[240:243], %[wp7], off\n\t"
        "global_load_dwordx4 v[244:247], %[wp7], off offset:16\n\t"
        "global_load_dwordx4 v[248:251], %[wp7], off offset:32\n\t"
        "global_load_dwordx4 v[252:255], %[wp7], off offset:48\n\t"
        "global_load_dword v97,  v[100:101], off offset:-2048\n\t"  // row 0
        "global_load_dword v103, v[100:101], off offset:-1024\n\t"  // row 1
        "v_and_b32 v88, 1, %[vo]\n\t"
        "v_cmp_eq_u32 s[24:25], 1, v88\n\t"
        "v_and_b32 v88, 2, %[vo]\n\t"
        "v_cmp_eq_u32 s[26:27], 2, v88\n\t"
        "v_and_b32 v88, 4, %[vo]\n\t"
        "v_cmp_eq_u32 s[28:29], 4, v88\n\t"
        "v_cmp_gt_u32 s[22:23], 8, %[vo]\n\t"
        "s_movk_i32 s30, 0x400\n\t"
        "s_waitcnt vmcnt(0)\n\t"
        // ---- main loop: 1024 iterations x 2 steps; ptr = row t+2 at half A
        "RNN%=:\n\t"
        // half A top: prefetch row t+2 -> v102 (last iter: dummy row 2047)
        "s_cmp_eq_u32 s30, 1\n\t"
        "s_cbranch_scc1 LDA%=\n\t"
        "global_load_dword v102, v[100:101], off\n\t"
        "s_branch LCA%=\n\t"
        "LDA%=:\n\t"
        "global_load_dword v102, v[100:101], off offset:-1024\n\t"
        "LCA%=:\n\t"
        MAC_ASM("%[rda]")
        RED_ASM
        FIN_ASM("%[wra]", "v97", "v98", "v103")
        // half B top: prefetch row t+3 -> v103 (last iter: dummy row 2047)
        "s_cmp_eq_u32 s30, 1\n\t"
        "s_cbranch_scc1 LDB%=\n\t"
        "global_load_dword v103, v[100:101], off\n\t"
        "s_branch LCB%=\n\t"
        "LDB%=:\n\t"
        "global_load_dword v103, v[100:101], off offset:-2048\n\t"
        "LCB%=:\n\t"
        MAC_ASM("%[rdb]")
        RED_ASM
        FIN_ASM("%[wrb]", "v98", "v97", "v102")
        "s_sub_u32 s30, s30, 1\n\t"
        "s_cmp_lg_u32 s30, 0\n\t"
        "s_cbranch_scc1 RNN%=\n\t"
        "s_waitcnt vmcnt(0) lgkmcnt(0)\n\t"
        :
        : [wp0] "v"(wp0), [wp1] "v"(wp1), [wp2] "v"(wp2), [wp3] "v"(wp3),
          [wp4] "v"(wp4), [wp5] "v"(wp5), [wp6] "v"(wp6), [wp7] "v"(wp7),
          [xlo] "v"(xlo), [xhi] "v"(xhi),
          [rda] "v"(rda), [rdb] "v"(rdb), [wra] "v"(wra), [wrb] "v"(wrb),
          [vo]  "v"(o)
        : "memory", "vcc", "scc",
          "s20","s21","s22","s23","s24","s25","s26","s27","s28","s29","s30",
          "v48","v49","v50","v51","v52","v53","v54","v55",
          "v56","v57","v58","v59","v60","v61","v62","v63",
          "v64","v65","v66","v67","v68","v69","v70","v71",
          "v72","v73","v74","v75","v76","v77","v78","v79",
          "v80","v81","v82","v83","v84","v85","v86","v87",
          "v88","v89","v90","v91","v92","v93","v94","v95",
          "v96","v97","v98","v99","v100","v101","v102","v103",
          "v104","v105","v106","v107","v108","v109","v110","v111",
          "v112","v113","v114","v115","v116","v117","v118","v119",
          "v120","v121","v122","v123","v124","v125","v126","v127",
          "v128","v129","v130","v131","v132","v133","v134","v135",
          "v136","v137","v138","v139","v140","v141","v142","v143",
          "v144","v145","v146","v147","v148","v149","v150","v151",
          "v152","v153","v154","v155","v156","v157","v158","v159",
          "v160","v161","v162","v163","v164","v165","v166","v167",
          "v168","v169","v170","v171","v172","v173","v174","v175",
          "v176","v177","v178","v179","v180","v181","v182","v183",
          "v184","v185","v186","v187","v188","v189","v190","v191",
          "v192","v193","v194","v195","v196","v197","v198","v199",
          "v200","v201","v202","v203","v204","v205","v206","v207",
          "v208","v209","v210","v211","v212","v213","v214","v215",
          "v216","v217","v218","v219","v220","v221","v222","v223",
          "v224","v225","v226","v227","v228","v229","v230","v231",
          "v232","v233","v234","v235","v236","v237","v238","v239",
          "v240","v241","v242","v243","v244","v245","v246","v247",
          "v248","v249","v250","v251","v252","v253","v254","v255");
}

extern "C" void kernel_launch(void* const* d_in, const int* in_sizes, int n_in,
                              void* d_out, int out_size, void* d_ws, size_t ws_size,
                              hipStream_t stream) {
    const int*   x     = (const int*)d_in[0];
    const float* embed = (const float*)d_in[1];
    const float* Wx    = (const float*)d_in[2];
    const float* Wxb   = (const float*)d_in[3];
    const float* Wh    = (const float*)d_in[4];
    float* out = (float*)d_out;

    const int nrows = BATCH * SEQ;                  // 131072, 32 rows/block
    xpre_kernel<<<nrows / 32, 256, 0, stream>>>(x, embed, Wx, Wxb, out);

    rnn_scan_kernel<<<BATCH, 512, 0, stream>>>(Wh, out);
}